// Round 6
// baseline (1685.598 us; speedup 1.0000x reference)
//
#include <hip/hip_runtime.h>
#include <math.h>

#define HIDDEN 100
#define HEADS 8
#define D 800          // HIDDEN*HEADS
#define ALPHA 0.2f

typedef unsigned short ushort;
typedef unsigned int uint;
typedef __attribute__((ext_vector_type(8))) short bf16x8;
typedef __attribute__((ext_vector_type(4))) float f32x4;

__device__ inline float bf2f(ushort u) { uint x = ((uint)u) << 16; return __uint_as_float(x); }
__device__ inline ushort f2bf(float f) {
    uint u = __float_as_uint(f);
    u += 0x7FFF + ((u >> 16) & 1);   // round-to-nearest-even
    return (ushort)(u >> 16);
}

// async global->LDS, 16B per lane; LDS dest must be the WAVE-UNIFORM base (HW adds lane*16)
__device__ inline void gl_lds16(const void* g, void* l) {
    __builtin_amdgcn_global_load_lds((const __attribute__((address_space(1))) void*)g,
                                     (__attribute__((address_space(3))) void*)l, 16, 0, 0);
}

// ---------- CSR row_ptr from sorted src via binary search ----------
__global__ void k_rowptr(const int* __restrict__ src, int E, int n, int* __restrict__ row_ptr) {
    int i = blockIdx.x * blockDim.x + threadIdx.x;
    if (i > n) return;
    int lo = 0, hi = E;
    while (lo < hi) { int mid = (lo + hi) >> 1; if (src[mid] < i) lo = mid + 1; else hi = mid; }
    row_ptr[i] = lo;
}

// ---------- repack kernels (3,8,800,100) -> per-layer transposed split bf16 ----------
// Bsp layout: [layer][2(hi,lo)][n=800][k=800] bf16, Bt[n][k] = kin[l, n/100, k, n%100]
__global__ void k_repack(const float* __restrict__ kin, ushort* __restrict__ bsp) {
    int gid = blockIdx.x * blockDim.x + threadIdx.x;
    if (gid >= 3 * D * D) return;
    int l = gid / (D * D);
    int rem = gid % (D * D);
    int nn = rem / D;        // output col (n)
    int k = rem % D;         // output row in k
    int h = nn / HIDDEN, c = nn % HIDDEN;
    float v = kin[((size_t)(l * HEADS + h) * D + k) * HIDDEN + c];
    ushort hi = f2bf(v);
    ushort lo = f2bf(v - bf2f(hi));
    size_t base = ((size_t)l * 2 * D + nn) * D + k;
    bsp[base] = hi;
    bsp[base + (size_t)D * D] = lo;
}

// ---------- x = relu(ns @ W_pre + b_pre), K=32; output split bf16 planes ----------
__global__ __launch_bounds__(256) void k_pre(const float* __restrict__ ns, const float* __restrict__ W,
                                             const float* __restrict__ b, ushort* __restrict__ xh,
                                             ushort* __restrict__ xl, int n) {
    int j = blockIdx.x * 256 + threadIdx.x;
    if (j >= D) return;
    float wk[32];
#pragma unroll
    for (int k = 0; k < 32; k++) wk[k] = W[k * D + j];
    float bj = b[j];
    int r0 = blockIdx.y * 32;
    int r1 = min(r0 + 32, n);
    for (int r = r0; r < r1; r++) {
        float acc = bj;
#pragma unroll
        for (int k = 0; k < 32; k++) acc += ns[r * 32 + k] * wk[k];
        acc = fmaxf(acc, 0.f);
        ushort h = f2bf(acc);
        xh[(size_t)r * D + j] = h;
        xl[(size_t)r * D + j] = f2bf(acc - bf2f(h));
    }
}

// ---------- Ht[M x 800](bf16) = (xh+xl)[M x 800] @ B[800 x 800], MFMA 3-pass compensated ----------
// BM=128 BN=160 BK=32; 4 waves (2x2); double-buffered LDS, fragment-ordered;
// ALL staging via global_load_lds (A pre-split into planes); XCD-aware block swizzle.
__global__ __launch_bounds__(256) void k_gemm(const ushort* __restrict__ xh, const ushort* __restrict__ xl,
                                              const ushort* __restrict__ Bsp, ushort* __restrict__ C, int M) {
    // fragment-ordered tiles: 512 ushorts (1024B) per 16x32 tile, linear in lane*16B
    __shared__ __align__(16) ushort Af[2][16 * 512];   // tiles 0..7 hi, 8..15 lo (32 KB)
    __shared__ __align__(16) ushort Bf[2][20 * 512];   // tiles 0..9 hi, 10..19 lo (40 KB)

    int d = blockIdx.x;
    int q = d & 7, m = d >> 3;      // XCD swizzle: same row-block -> same XCD
    int c = m % 5, j = m / 5;
    int r = j * 8 + q;
    int nrb = (M + 127) >> 7;
    if (r >= nrb) return;
    int row0 = r * 128, col0 = c * 160;

    int t = threadIdx.x;
    int w = t >> 6, lane = t & 63;
    int wr = w >> 1, wc = w & 1;
    int l15 = lane & 15, ks = lane >> 4;

    // staging assignments: per wave 4 A-tiles + 5 B-tiles
    const ushort* srcA[4];
    int ldsA[4];
#pragma unroll
    for (int i = 0; i < 4; i++) {
        int g = i * 4 + w;          // 0..15
        int mat = g >> 3, tile = g & 7;
        int row = min(row0 + tile * 16 + l15, M - 1);
        srcA[i] = (mat ? xl : xh) + (size_t)row * D + ks * 8;
        ldsA[i] = g * 512;
    }
    const ushort* srcB[5];
    int ldsB[5];
#pragma unroll
    for (int i = 0; i < 5; i++) {
        int g = i * 4 + w;          // 0..19
        int mat = (g >= 10) ? 1 : 0;
        int tile = g - mat * 10;
        int col = col0 + tile * 16 + l15;
        srcB[i] = Bsp + (size_t)mat * D * D + (size_t)col * D + ks * 8;
        ldsB[i] = g * 512;
    }

    f32x4 acc[4][5] = {};

    auto stage = [&](int buf, int k0) {
#pragma unroll
        for (int i = 0; i < 4; i++) gl_lds16(srcA[i] + k0, &Af[buf][ldsA[i]]);
#pragma unroll
        for (int i = 0; i < 5; i++) gl_lds16(srcB[i] + k0, &Bf[buf][ldsB[i]]);
    };
    auto compute = [&](int buf) {
        bf16x8 bh[5], bl[5];
#pragma unroll
        for (int ni = 0; ni < 5; ni++) {
            int tb = wc * 5 + ni;
            bh[ni] = *(const bf16x8*)&Bf[buf][tb * 512 + lane * 8];
            bl[ni] = *(const bf16x8*)&Bf[buf][(10 + tb) * 512 + lane * 8];
        }
#pragma unroll
        for (int mi = 0; mi < 4; mi++) {
            int tA = wr * 4 + mi;
            bf16x8 ah = *(const bf16x8*)&Af[buf][tA * 512 + lane * 8];
            bf16x8 al = *(const bf16x8*)&Af[buf][(8 + tA) * 512 + lane * 8];
#pragma unroll
            for (int ni = 0; ni < 5; ni++) {
                acc[mi][ni] = __builtin_amdgcn_mfma_f32_16x16x32_bf16(ah, bh[ni], acc[mi][ni], 0, 0, 0);
                acc[mi][ni] = __builtin_amdgcn_mfma_f32_16x16x32_bf16(al, bh[ni], acc[mi][ni], 0, 0, 0);
                acc[mi][ni] = __builtin_amdgcn_mfma_f32_16x16x32_bf16(ah, bl[ni], acc[mi][ni], 0, 0, 0);
            }
        }
    };

    stage(0, 0);
    __syncthreads();                      // buf0 ready
    for (int kt = 0; kt < 25; kt++) {
        if (kt < 24) stage((kt + 1) & 1, (kt + 1) * 32);   // loads fly during compute
        compute(kt & 1);
        __syncthreads();                  // drains vmcnt+lgkm: next buf ready, cur buf reusable
    }

    // C/D layout: col = lane&15, row = (lane>>4)*4 + reg   [m89-verified]
#pragma unroll
    for (int mi = 0; mi < 4; mi++) {
#pragma unroll
        for (int ni = 0; ni < 5; ni++) {
            int gr0 = row0 + wr * 64 + mi * 16 + ks * 4;
            int gc = col0 + wc * 80 + ni * 16 + l15;
#pragma unroll
            for (int rr = 0; rr < 4; rr++) {
                int gr = gr0 + rr;
                if (gr < M) C[(size_t)gr * D + gc] = f2bf(acc[mi][ni][rr]);
            }
        }
    }
}

// ---------- s,t per (node, head) from bf16 Ht ----------
__global__ __launch_bounds__(256) void k_st(const ushort* __restrict__ Ht, const float* __restrict__ att_l,
                                            float* __restrict__ s_all, float* __restrict__ t_all, int n) {
    int gid = blockIdx.x * blockDim.x + threadIdx.x;
    if (gid >= n * HEADS) return;
    int i = gid >> 3, h = gid & 7;
    const uint2* hp2 = (const uint2*)(Ht + (size_t)i * D + h * HIDDEN);
    const float* As = att_l + h * 2 * HIDDEN;
    const float* At = As + HIDDEN;
    float s = 0.f, t = 0.f;
#pragma unroll 5
    for (int q = 0; q < 25; q++) {
        uint2 v = hp2[q];
        float f0 = bf2f((ushort)(v.x & 0xFFFF)), f1 = bf2f((ushort)(v.x >> 16));
        float f2 = bf2f((ushort)(v.y & 0xFFFF)), f3 = bf2f((ushort)(v.y >> 16));
        int c = q * 4;
        s += f0 * As[c] + f1 * As[c + 1] + f2 * As[c + 2] + f3 * As[c + 3];
        t += f0 * At[c] + f1 * At[c + 1] + f2 * At[c + 2] + f3 * At[c + 3];
    }
    s_all[gid] = s;
    t_all[gid] = t;
}

// ---------- per-node segment softmax + aggregate + relu + residual (x planes in-place) ----------
__global__ __launch_bounds__(256) void k_edge(const ushort* __restrict__ Ht, ushort* __restrict__ xh,
                                              ushort* __restrict__ xl,
                                              const float* __restrict__ s_all, const float* __restrict__ t_all,
                                              const int* __restrict__ dst, const int* __restrict__ row_ptr,
                                              int n) {
    int i = blockIdx.x;
    int t = threadIdx.x;
    __shared__ float lw[32][8];
    __shared__ int ld[32];
    int e0 = row_ptr[i], e1 = row_ptr[i + 1];
    int h = t / 25;            // head for aggregation (valid for t<200)
    int el = t >> 3, hh = t & 7;
    float s_ih = s_all[i * 8 + hh];
    float acc0 = 0, acc1 = 0, acc2 = 0, acc3 = 0, den = 0;

    for (int base = e0; base < e1; base += 32) {
        int cnt = min(32, e1 - base);
        __syncthreads();
        if (el < cnt) {
            int dd = dst[base + el];
            float ev = s_ih + t_all[dd * 8 + hh];
            ev = ev >= 0.f ? ev : ALPHA * ev;
            ev = fminf(fmaxf(ev, -2.f), 2.f);
            lw[el][hh] = __expf(ev);
            if (hh == 0) ld[el] = dd;
        }
        __syncthreads();
        if (t < 200) {
#pragma unroll 4
            for (int e = 0; e < cnt; e++) {
                int dd = ld[e];
                uint2 v = *(const uint2*)(Ht + (size_t)dd * D + t * 4);
                float wgt = lw[e][h];
                acc0 += wgt * bf2f((ushort)(v.x & 0xFFFF));
                acc1 += wgt * bf2f((ushort)(v.x >> 16));
                acc2 += wgt * bf2f((ushort)(v.y & 0xFFFF));
                acc3 += wgt * bf2f((ushort)(v.y >> 16));
                den += wgt;
            }
        }
    }
    if (t < 200) {
        size_t off = (size_t)i * D + t * 4;
        uint2 vh = *(uint2*)(xh + off);
        uint2 vl = *(uint2*)(xl + off);
        float x0 = bf2f((ushort)(vh.x & 0xFFFF)) + bf2f((ushort)(vl.x & 0xFFFF));
        float x1 = bf2f((ushort)(vh.x >> 16))    + bf2f((ushort)(vl.x >> 16));
        float x2 = bf2f((ushort)(vh.y & 0xFFFF)) + bf2f((ushort)(vl.y & 0xFFFF));
        float x3 = bf2f((ushort)(vh.y >> 16))    + bf2f((ushort)(vl.y >> 16));
        float inv = den > 0.f ? 1.f / den : 0.f;
        x0 += fmaxf(acc0 * inv, 0.f);
        x1 += fmaxf(acc1 * inv, 0.f);
        x2 += fmaxf(acc2 * inv, 0.f);
        x3 += fmaxf(acc3 * inv, 0.f);
        ushort h0 = f2bf(x0), h1 = f2bf(x1), h2 = f2bf(x2), h3 = f2bf(x3);
        ushort l0 = f2bf(x0 - bf2f(h0)), l1 = f2bf(x1 - bf2f(h1));
        ushort l2 = f2bf(x2 - bf2f(h2)), l3 = f2bf(x3 - bf2f(h3));
        *(uint2*)(xh + off) = make_uint2((uint)h0 | ((uint)h1 << 16), (uint)h2 | ((uint)h3 << 16));
        *(uint2*)(xl + off) = make_uint2((uint)l0 | ((uint)l1 << 16), (uint)l2 | ((uint)l3 << 16));
    }
}

// ---------- final stage A: per-block partial of sum_i (x_i . Wl + bl) * Wc_i ----------
__global__ __launch_bounds__(256) void k_final(const ushort* __restrict__ xh, const ushort* __restrict__ xl,
                                               const float* __restrict__ Wl, const float* __restrict__ bl,
                                               const float* __restrict__ Wc, float* __restrict__ fpart, int n) {
    __shared__ float part[4];
    int lane = threadIdx.x & 63, w = threadIdx.x >> 6;
    int wid = blockIdx.x * 4 + w;
    int nw = gridDim.x * 4;
    float p = 0.f;
    for (int i = wid; i < n; i += nw) {
        float dot = 0.f;
#pragma unroll
        for (int r = 0; r < 13; r++) {
            int j = r * 64 + lane;
            if (j < D) {
                size_t off = (size_t)i * D + j;
                dot += (bf2f(xh[off]) + bf2f(xl[off])) * Wl[j];
            }
        }
#pragma unroll
        for (int off = 32; off; off >>= 1) dot += __shfl_xor(dot, off);
        if (lane == 0) p += (dot + bl[0]) * Wc[i];
    }
    if (lane == 0) part[w] = p;
    __syncthreads();
    if (threadIdx.x == 0) fpart[blockIdx.x] = part[0] + part[1] + part[2] + part[3];
}

// ---------- final stage B ----------
__global__ __launch_bounds__(64) void k_reduce(const float* __restrict__ fpart, const float* __restrict__ bc,
                                               float* __restrict__ out, int nb) {
    if (threadIdx.x == 0) {
        float s = 0.f;
        for (int q = 0; q < nb; q++) s += fpart[q];
        out[0] = s + bc[0];
    }
}

// ---------- sentinel if workspace too small ----------
__global__ void k_sentinel(float* out) { out[0] = 12345.0f; }

extern "C" void kernel_launch(void* const* d_in, const int* in_sizes, int n_in,
                              void* d_out, int out_size, void* d_ws, size_t ws_size,
                              hipStream_t stream) {
    const float* ns   = (const float*)d_in[0];
    const int*   src  = (const int*)d_in[1];
    const int*   dst  = (const int*)d_in[2];
    const float* Wpre = (const float*)d_in[3];
    const float* bpre = (const float*)d_in[4];
    const float* kern = (const float*)d_in[5];
    const float* att  = (const float*)d_in[6];
    const float* Wl   = (const float*)d_in[7];
    const float* bl   = (const float*)d_in[8];
    const float* Wc   = (const float*)d_in[9];
    const float* bc   = (const float*)d_in[10];
    int n = in_sizes[9];   // Wc has n elements
    int E = in_sizes[1];

    size_t need = 0;
    auto sz = [&](size_t bytes) { size_t o = need; need += (bytes + 255) & ~255ull; return o; };
    size_t o_xh    = sz((size_t)n * D * 2);          // bf16 hi plane of x
    size_t o_xl    = sz((size_t)n * D * 2);          // bf16 lo plane of x
    size_t o_Ht    = sz((size_t)n * D * 2);          // bf16 Ht
    size_t o_bsp   = sz(3ull * 2 * D * D * 2);       // bf16 split+transposed weights
    size_t o_s     = sz((size_t)n * 8 * 4);
    size_t o_t     = sz((size_t)n * 8 * 4);
    size_t o_rp    = sz(((size_t)n + 1) * 4);
    size_t o_fp    = sz(128 * 4);

    if (need > ws_size) {   // diagnostic: absmax will be ~12345
        k_sentinel<<<1, 1, 0, stream>>>((float*)d_out);
        return;
    }

    char* ws = (char*)d_ws;
    ushort* xh    = (ushort*)(ws + o_xh);
    ushort* xl    = (ushort*)(ws + o_xl);
    ushort* Ht    = (ushort*)(ws + o_Ht);
    ushort* bsp   = (ushort*)(ws + o_bsp);
    float*  s_all = (float*)(ws + o_s);
    float*  t_all = (float*)(ws + o_t);
    int*    row_ptr = (int*)(ws + o_rp);
    float*  fpart = (float*)(ws + o_fp);

    k_rowptr<<<(n + 1 + 255) / 256, 256, 0, stream>>>(src, E, n, row_ptr);
    k_repack<<<(3 * D * D + 255) / 256, 256, 0, stream>>>(kern, bsp);
    dim3 gpre((D + 255) / 256, (n + 31) / 32);
    k_pre<<<gpre, 256, 0, stream>>>(ns, Wpre, bpre, xh, xl, n);

    int nrb = (n + 127) / 128;                    // 391 row blocks
    int grid_g = 8 * (((nrb + 7) / 8) * 5);       // swizzle-decoded inside kernel
    for (int l = 0; l < 3; l++) {
        k_gemm<<<grid_g, 256, 0, stream>>>(xh, xl, bsp + (size_t)l * 2 * D * D, Ht, n);
        k_st<<<(n * HEADS + 255) / 256, 256, 0, stream>>>(Ht, att + l * HEADS * 2 * HIDDEN, s_all, t_all, n);
        k_edge<<<n, 256, 0, stream>>>(Ht, xh, xl, s_all, t_all, dst, row_ptr, n);
    }

    k_final<<<120, 256, 0, stream>>>(xh, xl, Wl, bl, Wc, fpart, n);
    k_reduce<<<1, 64, 0, stream>>>(fpart, bc, (float*)d_out, 120);
}

// Round 7
// 1642.052 us; speedup vs baseline: 1.0265x; 1.0265x over previous
//
#include <hip/hip_runtime.h>
#include <math.h>

#define HIDDEN 100
#define HEADS 8
#define D 800          // HIDDEN*HEADS
#define ALPHA 0.2f

typedef unsigned short ushort;
typedef unsigned int uint;
typedef __attribute__((ext_vector_type(8))) short bf16x8;
typedef __attribute__((ext_vector_type(4))) float f32x4;

__device__ inline float bf2f(ushort u) { uint x = ((uint)u) << 16; return __uint_as_float(x); }
__device__ inline ushort f2bf(float f) {
    uint u = __float_as_uint(f);
    u += 0x7FFF + ((u >> 16) & 1);   // round-to-nearest-even
    return (ushort)(u >> 16);
}

// async global->LDS, 16B per lane; LDS dest must be the WAVE-UNIFORM base (HW adds lane*16)
__device__ inline void gl_lds16(const void* g, void* l) {
    __builtin_amdgcn_global_load_lds((const __attribute__((address_space(1))) void*)g,
                                     (__attribute__((address_space(3))) void*)l, 16, 0, 0);
}

// ---------- CSR row_ptr from sorted src via binary search ----------
__global__ void k_rowptr(const int* __restrict__ src, int E, int n, int* __restrict__ row_ptr) {
    int i = blockIdx.x * blockDim.x + threadIdx.x;
    if (i > n) return;
    int lo = 0, hi = E;
    while (lo < hi) { int mid = (lo + hi) >> 1; if (src[mid] < i) lo = mid + 1; else hi = mid; }
    row_ptr[i] = lo;
}

// ---------- repack kernels (3,8,800,100) -> per-layer transposed split bf16 ----------
// Bsp layout: [layer][2(hi,lo)][n=800][k=800] bf16, Bt[n][k] = kin[l, n/100, k, n%100]
__global__ void k_repack(const float* __restrict__ kin, ushort* __restrict__ bsp) {
    int gid = blockIdx.x * blockDim.x + threadIdx.x;
    if (gid >= 3 * D * D) return;
    int l = gid / (D * D);
    int rem = gid % (D * D);
    int nn = rem / D;        // output col (n)
    int k = rem % D;         // output row in k
    int h = nn / HIDDEN, c = nn % HIDDEN;
    float v = kin[((size_t)(l * HEADS + h) * D + k) * HIDDEN + c];
    ushort hi = f2bf(v);
    ushort lo = f2bf(v - bf2f(hi));
    size_t base = ((size_t)l * 2 * D + nn) * D + k;
    bsp[base] = hi;
    bsp[base + (size_t)D * D] = lo;
}

// ---------- x = relu(ns @ W_pre + b_pre), K=32; output split bf16 planes ----------
__global__ __launch_bounds__(256) void k_pre(const float* __restrict__ ns, const float* __restrict__ W,
                                             const float* __restrict__ b, ushort* __restrict__ xh,
                                             ushort* __restrict__ xl, int n) {
    int j = blockIdx.x * 256 + threadIdx.x;
    if (j >= D) return;
    float wk[32];
#pragma unroll
    for (int k = 0; k < 32; k++) wk[k] = W[k * D + j];
    float bj = b[j];
    int r0 = blockIdx.y * 32;
    int r1 = min(r0 + 32, n);
    for (int r = r0; r < r1; r++) {
        float acc = bj;
#pragma unroll
        for (int k = 0; k < 32; k++) acc += ns[r * 32 + k] * wk[k];
        acc = fmaxf(acc, 0.f);
        ushort h = f2bf(acc);
        xh[(size_t)r * D + j] = h;
        xl[(size_t)r * D + j] = f2bf(acc - bf2f(h));
    }
}

// ---------- Ht[M x 800](bf16) = (xh+xl)[M x 800] @ B[800 x 800], MFMA 3-pass compensated ----------
// BM=128 BN=160 BK=32; 4 waves (2x2); double-buffered LDS, fragment-ordered;
// ALL staging via global_load_lds; T4 counted-vmcnt pipeline (loads stay in flight across barriers).
__global__ __launch_bounds__(256) void k_gemm(const ushort* __restrict__ xh, const ushort* __restrict__ xl,
                                              const ushort* __restrict__ Bsp, ushort* __restrict__ C, int M) {
    // fragment-ordered tiles: 512 ushorts (1024B) per 16x32 tile, linear in lane*16B
    __shared__ __align__(16) ushort Af[2][16 * 512];   // tiles 0..7 hi, 8..15 lo (32 KB)
    __shared__ __align__(16) ushort Bf[2][20 * 512];   // tiles 0..9 hi, 10..19 lo (40 KB)

    int d = blockIdx.x;
    int q = d & 7, m = d >> 3;      // XCD swizzle: same row-block -> same XCD
    int c = m % 5, j = m / 5;
    int r = j * 8 + q;
    int nrb = (M + 127) >> 7;
    if (r >= nrb) return;
    int row0 = r * 128, col0 = c * 160;

    int t = threadIdx.x;
    int w = t >> 6, lane = t & 63;
    int wr = w >> 1, wc = w & 1;
    int l15 = lane & 15, ks = lane >> 4;

    // staging assignments: per wave 4 A-tiles + 5 B-tiles (9 VMEM ops per wave per K-tile)
    const ushort* srcA[4];
    int ldsA[4];
#pragma unroll
    for (int i = 0; i < 4; i++) {
        int g = i * 4 + w;          // 0..15
        int mat = g >> 3, tile = g & 7;
        int row = min(row0 + tile * 16 + l15, M - 1);
        srcA[i] = (mat ? xl : xh) + (size_t)row * D + ks * 8;
        ldsA[i] = g * 512;
    }
    const ushort* srcB[5];
    int ldsB[5];
#pragma unroll
    for (int i = 0; i < 5; i++) {
        int g = i * 4 + w;          // 0..19
        int mat = (g >= 10) ? 1 : 0;
        int tile = g - mat * 10;
        int col = col0 + tile * 16 + l15;
        srcB[i] = Bsp + (size_t)mat * D * D + (size_t)col * D + ks * 8;
        ldsB[i] = g * 512;
    }

    f32x4 acc[4][5] = {};

    auto stage = [&](int buf, int k0) {
#pragma unroll
        for (int i = 0; i < 4; i++) gl_lds16(srcA[i] + k0, &Af[buf][ldsA[i]]);
#pragma unroll
        for (int i = 0; i < 5; i++) gl_lds16(srcB[i] + k0, &Bf[buf][ldsB[i]]);
    };
    auto compute = [&](int buf) {
        bf16x8 bh[5], bl[5];
#pragma unroll
        for (int ni = 0; ni < 5; ni++) {
            int tb = wc * 5 + ni;
            bh[ni] = *(const bf16x8*)&Bf[buf][tb * 512 + lane * 8];
            bl[ni] = *(const bf16x8*)&Bf[buf][(10 + tb) * 512 + lane * 8];
        }
#pragma unroll
        for (int mi = 0; mi < 4; mi++) {
            int tA = wr * 4 + mi;
            bf16x8 ah = *(const bf16x8*)&Af[buf][tA * 512 + lane * 8];
            bf16x8 al = *(const bf16x8*)&Af[buf][(8 + tA) * 512 + lane * 8];
#pragma unroll
            for (int ni = 0; ni < 5; ni++) {
                acc[mi][ni] = __builtin_amdgcn_mfma_f32_16x16x32_bf16(ah, bh[ni], acc[mi][ni], 0, 0, 0);
                acc[mi][ni] = __builtin_amdgcn_mfma_f32_16x16x32_bf16(al, bh[ni], acc[mi][ni], 0, 0, 0);
                acc[mi][ni] = __builtin_amdgcn_mfma_f32_16x16x32_bf16(ah, bl[ni], acc[mi][ni], 0, 0, 0);
            }
        }
    };

    stage(0, 0);                               // S_0 in flight (9 per wave)
    for (int kt = 0; kt < 25; kt++) {
        if (kt < 24) {
            stage((kt + 1) & 1, (kt + 1) * 32);              // S_{t+1}: up to 18 in flight
            asm volatile("s_waitcnt vmcnt(9)" ::: "memory"); // S_t landed; S_{t+1} STAYS in flight
        } else {
            asm volatile("s_waitcnt vmcnt(0)" ::: "memory"); // last tile: drain
        }
        __builtin_amdgcn_s_barrier();          // all waves' S_t landed (raw barrier, no drain)
        compute(kt & 1);
        __builtin_amdgcn_s_barrier();          // all waves done reading buf before it's re-staged
    }

    // C/D layout: col = lane&15, row = (lane>>4)*4 + reg   [m89-verified]
#pragma unroll
    for (int mi = 0; mi < 4; mi++) {
#pragma unroll
        for (int ni = 0; ni < 5; ni++) {
            int gr0 = row0 + wr * 64 + mi * 16 + ks * 4;
            int gc = col0 + wc * 80 + ni * 16 + l15;
#pragma unroll
            for (int rr = 0; rr < 4; rr++) {
                int gr = gr0 + rr;
                if (gr < M) C[(size_t)gr * D + gc] = f2bf(acc[mi][ni][rr]);
            }
        }
    }
}

// ---------- s,t per (node, head) from bf16 Ht ----------
__global__ __launch_bounds__(256) void k_st(const ushort* __restrict__ Ht, const float* __restrict__ att_l,
                                            float* __restrict__ s_all, float* __restrict__ t_all, int n) {
    int gid = blockIdx.x * blockDim.x + threadIdx.x;
    if (gid >= n * HEADS) return;
    int i = gid >> 3, h = gid & 7;
    const uint2* hp2 = (const uint2*)(Ht + (size_t)i * D + h * HIDDEN);
    const float* As = att_l + h * 2 * HIDDEN;
    const float* At = As + HIDDEN;
    float s = 0.f, t = 0.f;
#pragma unroll 5
    for (int q = 0; q < 25; q++) {
        uint2 v = hp2[q];
        float f0 = bf2f((ushort)(v.x & 0xFFFF)), f1 = bf2f((ushort)(v.x >> 16));
        float f2 = bf2f((ushort)(v.y & 0xFFFF)), f3 = bf2f((ushort)(v.y >> 16));
        int c = q * 4;
        s += f0 * As[c] + f1 * As[c + 1] + f2 * As[c + 2] + f3 * As[c + 3];
        t += f0 * At[c] + f1 * At[c + 1] + f2 * At[c + 2] + f3 * At[c + 3];
    }
    s_all[gid] = s;
    t_all[gid] = t;
}

// ---------- per-node segment softmax + aggregate + relu + residual (x planes in-place) ----------
__global__ __launch_bounds__(256) void k_edge(const ushort* __restrict__ Ht, ushort* __restrict__ xh,
                                              ushort* __restrict__ xl,
                                              const float* __restrict__ s_all, const float* __restrict__ t_all,
                                              const int* __restrict__ dst, const int* __restrict__ row_ptr,
                                              int n) {
    int i = blockIdx.x;
    int t = threadIdx.x;
    __shared__ float lw[32][8];
    __shared__ int ld[32];
    int e0 = row_ptr[i], e1 = row_ptr[i + 1];
    int h = t / 25;            // head for aggregation (valid for t<200)
    int el = t >> 3, hh = t & 7;
    float s_ih = s_all[i * 8 + hh];
    float acc0 = 0, acc1 = 0, acc2 = 0, acc3 = 0, den = 0;

    for (int base = e0; base < e1; base += 32) {
        int cnt = min(32, e1 - base);
        __syncthreads();
        if (el < cnt) {
            int dd = dst[base + el];
            float ev = s_ih + t_all[dd * 8 + hh];
            ev = ev >= 0.f ? ev : ALPHA * ev;
            ev = fminf(fmaxf(ev, -2.f), 2.f);
            lw[el][hh] = __expf(ev);
            if (hh == 0) ld[el] = dd;
        }
        __syncthreads();
        if (t < 200) {
#pragma unroll 4
            for (int e = 0; e < cnt; e++) {
                int dd = ld[e];
                uint2 v = *(const uint2*)(Ht + (size_t)dd * D + t * 4);
                float wgt = lw[e][h];
                acc0 += wgt * bf2f((ushort)(v.x & 0xFFFF));
                acc1 += wgt * bf2f((ushort)(v.x >> 16));
                acc2 += wgt * bf2f((ushort)(v.y & 0xFFFF));
                acc3 += wgt * bf2f((ushort)(v.y >> 16));
                den += wgt;
            }
        }
    }
    if (t < 200) {
        size_t off = (size_t)i * D + t * 4;
        uint2 vh = *(uint2*)(xh + off);
        uint2 vl = *(uint2*)(xl + off);
        float x0 = bf2f((ushort)(vh.x & 0xFFFF)) + bf2f((ushort)(vl.x & 0xFFFF));
        float x1 = bf2f((ushort)(vh.x >> 16))    + bf2f((ushort)(vl.x >> 16));
        float x2 = bf2f((ushort)(vh.y & 0xFFFF)) + bf2f((ushort)(vl.y & 0xFFFF));
        float x3 = bf2f((ushort)(vh.y >> 16))    + bf2f((ushort)(vl.y >> 16));
        float inv = den > 0.f ? 1.f / den : 0.f;
        x0 += fmaxf(acc0 * inv, 0.f);
        x1 += fmaxf(acc1 * inv, 0.f);
        x2 += fmaxf(acc2 * inv, 0.f);
        x3 += fmaxf(acc3 * inv, 0.f);
        ushort h0 = f2bf(x0), h1 = f2bf(x1), h2 = f2bf(x2), h3 = f2bf(x3);
        ushort l0 = f2bf(x0 - bf2f(h0)), l1 = f2bf(x1 - bf2f(h1));
        ushort l2 = f2bf(x2 - bf2f(h2)), l3 = f2bf(x3 - bf2f(h3));
        *(uint2*)(xh + off) = make_uint2((uint)h0 | ((uint)h1 << 16), (uint)h2 | ((uint)h3 << 16));
        *(uint2*)(xl + off) = make_uint2((uint)l0 | ((uint)l1 << 16), (uint)l2 | ((uint)l3 << 16));
    }
}

// ---------- final stage A: per-block partial of sum_i (x_i . Wl + bl) * Wc_i ----------
__global__ __launch_bounds__(256) void k_final(const ushort* __restrict__ xh, const ushort* __restrict__ xl,
                                               const float* __restrict__ Wl, const float* __restrict__ bl,
                                               const float* __restrict__ Wc, float* __restrict__ fpart, int n) {
    __shared__ float part[4];
    int lane = threadIdx.x & 63, w = threadIdx.x >> 6;
    int wid = blockIdx.x * 4 + w;
    int nw = gridDim.x * 4;
    float p = 0.f;
    for (int i = wid; i < n; i += nw) {
        float dot = 0.f;
#pragma unroll
        for (int r = 0; r < 13; r++) {
            int j = r * 64 + lane;
            if (j < D) {
                size_t off = (size_t)i * D + j;
                dot += (bf2f(xh[off]) + bf2f(xl[off])) * Wl[j];
            }
        }
#pragma unroll
        for (int off = 32; off; off >>= 1) dot += __shfl_xor(dot, off);
        if (lane == 0) p += (dot + bl[0]) * Wc[i];
    }
    if (lane == 0) part[w] = p;
    __syncthreads();
    if (threadIdx.x == 0) fpart[blockIdx.x] = part[0] + part[1] + part[2] + part[3];
}

// ---------- final stage B ----------
__global__ __launch_bounds__(64) void k_reduce(const float* __restrict__ fpart, const float* __restrict__ bc,
                                               float* __restrict__ out, int nb) {
    if (threadIdx.x == 0) {
        float s = 0.f;
        for (int q = 0; q < nb; q++) s += fpart[q];
        out[0] = s + bc[0];
    }
}

// ---------- sentinel if workspace too small ----------
__global__ void k_sentinel(float* out) { out[0] = 12345.0f; }

extern "C" void kernel_launch(void* const* d_in, const int* in_sizes, int n_in,
                              void* d_out, int out_size, void* d_ws, size_t ws_size,
                              hipStream_t stream) {
    const float* ns   = (const float*)d_in[0];
    const int*   src  = (const int*)d_in[1];
    const int*   dst  = (const int*)d_in[2];
    const float* Wpre = (const float*)d_in[3];
    const float* bpre = (const float*)d_in[4];
    const float* kern = (const float*)d_in[5];
    const float* att  = (const float*)d_in[6];
    const float* Wl   = (const float*)d_in[7];
    const float* bl   = (const float*)d_in[8];
    const float* Wc   = (const float*)d_in[9];
    const float* bc   = (const float*)d_in[10];
    int n = in_sizes[9];   // Wc has n elements
    int E = in_sizes[1];

    size_t need = 0;
    auto sz = [&](size_t bytes) { size_t o = need; need += (bytes + 255) & ~255ull; return o; };
    size_t o_xh    = sz((size_t)n * D * 2);          // bf16 hi plane of x
    size_t o_xl    = sz((size_t)n * D * 2);          // bf16 lo plane of x
    size_t o_Ht    = sz((size_t)n * D * 2);          // bf16 Ht
    size_t o_bsp   = sz(3ull * 2 * D * D * 2);       // bf16 split+transposed weights
    size_t o_s     = sz((size_t)n * 8 * 4);
    size_t o_t     = sz((size_t)n * 8 * 4);
    size_t o_rp    = sz(((size_t)n + 1) * 4);
    size_t o_fp    = sz(128 * 4);

    if (need > ws_size) {   // diagnostic: absmax will be ~12345
        k_sentinel<<<1, 1, 0, stream>>>((float*)d_out);
        return;
    }

    char* ws = (char*)d_ws;
    ushort* xh    = (ushort*)(ws + o_xh);
    ushort* xl    = (ushort*)(ws + o_xl);
    ushort* Ht    = (ushort*)(ws + o_Ht);
    ushort* bsp   = (ushort*)(ws + o_bsp);
    float*  s_all = (float*)(ws + o_s);
    float*  t_all = (float*)(ws + o_t);
    int*    row_ptr = (int*)(ws + o_rp);
    float*  fpart = (float*)(ws + o_fp);

    k_rowptr<<<(n + 1 + 255) / 256, 256, 0, stream>>>(src, E, n, row_ptr);
    k_repack<<<(3 * D * D + 255) / 256, 256, 0, stream>>>(kern, bsp);
    dim3 gpre((D + 255) / 256, (n + 31) / 32);
    k_pre<<<gpre, 256, 0, stream>>>(ns, Wpre, bpre, xh, xl, n);

    int nrb = (n + 127) / 128;                    // 391 row blocks
    int grid_g = 8 * (((nrb + 7) / 8) * 5);       // swizzle-decoded inside kernel
    for (int l = 0; l < 3; l++) {
        k_gemm<<<grid_g, 256, 0, stream>>>(xh, xl, bsp + (size_t)l * 2 * D * D, Ht, n);
        k_st<<<(n * HEADS + 255) / 256, 256, 0, stream>>>(Ht, att + l * HEADS * 2 * HIDDEN, s_all, t_all, n);
        k_edge<<<n, 256, 0, stream>>>(Ht, xh, xl, s_all, t_all, dst, row_ptr, n);
    }

    k_final<<<120, 256, 0, stream>>>(xh, xl, Wl, bl, Wc, fpart, n);
    k_reduce<<<1, 64, 0, stream>>>(fpart, bc, (float*)d_out, 120);
}

// Round 8
// 1431.668 us; speedup vs baseline: 1.1774x; 1.1470x over previous
//
#include <hip/hip_runtime.h>
#include <math.h>

#define HIDDEN 100
#define HEADS 8
#define D 800          // HIDDEN*HEADS
#define ALPHA 0.2f

typedef unsigned short ushort;
typedef unsigned int uint;
typedef __attribute__((ext_vector_type(8))) short bf16x8;
typedef __attribute__((ext_vector_type(4))) float f32x4;

__device__ inline float bf2f(ushort u) { uint x = ((uint)u) << 16; return __uint_as_float(x); }
__device__ inline ushort f2bf(float f) {
    uint u = __float_as_uint(f);
    u += 0x7FFF + ((u >> 16) & 1);   // round-to-nearest-even
    return (ushort)(u >> 16);
}

// async global->LDS, 16B per lane; LDS dest must be the WAVE-UNIFORM base (HW adds lane*16)
__device__ inline void gl_lds16(const void* g, void* l) {
    __builtin_amdgcn_global_load_lds((const __attribute__((address_space(1))) void*)g,
                                     (__attribute__((address_space(3))) void*)l, 16, 0, 0);
}

// ---------- CSR row_ptr from sorted src via binary search ----------
__global__ void k_rowptr(const int* __restrict__ src, int E, int n, int* __restrict__ row_ptr) {
    int i = blockIdx.x * blockDim.x + threadIdx.x;
    if (i > n) return;
    int lo = 0, hi = E;
    while (lo < hi) { int mid = (lo + hi) >> 1; if (src[mid] < i) lo = mid + 1; else hi = mid; }
    row_ptr[i] = lo;
}

// ---------- repack kernels (3,8,800,100) -> per-layer transposed bf16 (hi plane only) ----------
// Bsp layout: [layer][n=800][k=800] bf16, Bt[n][k] = kin[l, n/100, k, n%100]
__global__ void k_repack(const float* __restrict__ kin, ushort* __restrict__ bsp) {
    int gid = blockIdx.x * blockDim.x + threadIdx.x;
    if (gid >= 3 * D * D) return;
    int l = gid / (D * D);
    int rem = gid % (D * D);
    int nn = rem / D;        // output col (n)
    int k = rem % D;         // output row in k
    int h = nn / HIDDEN, c = nn % HIDDEN;
    float v = kin[((size_t)(l * HEADS + h) * D + k) * HIDDEN + c];
    bsp[((size_t)l * D + nn) * D + k] = f2bf(v);
}

// ---------- x = relu(ns @ W_pre + b_pre), K=32; output split bf16 planes ----------
__global__ __launch_bounds__(256) void k_pre(const float* __restrict__ ns, const float* __restrict__ W,
                                             const float* __restrict__ b, ushort* __restrict__ xh,
                                             ushort* __restrict__ xl, int n) {
    int j = blockIdx.x * 256 + threadIdx.x;
    if (j >= D) return;
    float wk[32];
#pragma unroll
    for (int k = 0; k < 32; k++) wk[k] = W[k * D + j];
    float bj = b[j];
    int r0 = blockIdx.y * 32;
    int r1 = min(r0 + 32, n);
    for (int r = r0; r < r1; r++) {
        float acc = bj;
#pragma unroll
        for (int k = 0; k < 32; k++) acc += ns[r * 32 + k] * wk[k];
        acc = fmaxf(acc, 0.f);
        ushort h = f2bf(acc);
        xh[(size_t)r * D + j] = h;
        xl[(size_t)r * D + j] = f2bf(acc - bf2f(h));
    }
}

// ---------- Ht[M x 800](bf16) = (xh+xl)[M x 800] @ Bh[800 x 800], MFMA 2-pass compensated ----------
// BM=128 BN=160 BK=32; 4 waves (2x2); dbuf LDS 52KB -> 3 blocks/CU; all staging via
// global_load_lds; counted-vmcnt pipeline; XCD-aware block swizzle.
__global__ __launch_bounds__(256) void k_gemm(const ushort* __restrict__ xh, const ushort* __restrict__ xl,
                                              const ushort* __restrict__ Bsp, ushort* __restrict__ C, int M) {
    // fragment-ordered tiles: 512 ushorts (1024B) per 16x32 tile, linear in lane*16B
    __shared__ __align__(16) ushort Af[2][16 * 512];   // tiles 0..7 hi, 8..15 lo (32 KB)
    __shared__ __align__(16) ushort Bf[2][10 * 512];   // tiles 0..9 (B hi only, 20 KB)

    int d = blockIdx.x;
    int q = d & 7, m = d >> 3;      // XCD swizzle: same row-block -> same XCD
    int c = m % 5, j = m / 5;
    int r = j * 8 + q;
    int nrb = (M + 127) >> 7;
    if (r >= nrb) return;
    int row0 = r * 128, col0 = c * 160;

    int t = threadIdx.x;
    int w = t >> 6, lane = t & 63;
    int wr = w >> 1, wc = w & 1;
    int l15 = lane & 15, ks = lane >> 4;

    // staging: per wave 4 A-tiles + {2,2,3,3} B-tiles
    const ushort* srcA[4];
    int ldsA[4];
#pragma unroll
    for (int i = 0; i < 4; i++) {
        int g = i * 4 + w;          // 0..15
        int mat = g >> 3, tile = g & 7;
        int row = min(row0 + tile * 16 + l15, M - 1);
        srcA[i] = (mat ? xl : xh) + (size_t)row * D + ks * 8;
        ldsA[i] = g * 512;
    }
    int bcnt = (w < 2) ? 2 : 3;
    int bbase = (w < 2) ? 2 * w : 4 + 3 * (w - 2);   // wave0:{0,1} wave1:{2,3} wave2:{4,5,6} wave3:{7,8,9}
    const ushort* srcB[3];
    int ldsB[3];
#pragma unroll
    for (int i = 0; i < 3; i++) {
        int tile = bbase + i;
        if (tile > 9) tile = 9;
        int col = col0 + tile * 16 + l15;
        srcB[i] = Bsp + (size_t)col * D + ks * 8;
        ldsB[i] = tile * 512;
    }

    f32x4 acc[4][5] = {};

    auto stage = [&](int buf, int k0) {
#pragma unroll
        for (int i = 0; i < 4; i++) gl_lds16(srcA[i] + k0, &Af[buf][ldsA[i]]);
        for (int i = 0; i < bcnt; i++) gl_lds16(srcB[i] + k0, &Bf[buf][ldsB[i]]);
    };
    auto compute = [&](int buf) {
        bf16x8 bh[5];
#pragma unroll
        for (int ni = 0; ni < 5; ni++)
            bh[ni] = *(const bf16x8*)&Bf[buf][(wc * 5 + ni) * 512 + lane * 8];
#pragma unroll
        for (int mi = 0; mi < 4; mi++) {
            int tA = wr * 4 + mi;
            bf16x8 ah = *(const bf16x8*)&Af[buf][tA * 512 + lane * 8];
            bf16x8 al = *(const bf16x8*)&Af[buf][(8 + tA) * 512 + lane * 8];
#pragma unroll
            for (int ni = 0; ni < 5; ni++) {
                acc[mi][ni] = __builtin_amdgcn_mfma_f32_16x16x32_bf16(ah, bh[ni], acc[mi][ni], 0, 0, 0);
                acc[mi][ni] = __builtin_amdgcn_mfma_f32_16x16x32_bf16(al, bh[ni], acc[mi][ni], 0, 0, 0);
            }
        }
    };

    stage(0, 0);                               // S_0 in flight (6/7 per wave)
    for (int kt = 0; kt < 25; kt++) {
        if (kt < 24) {
            stage((kt + 1) & 1, (kt + 1) * 32);   // S_{t+1} stays in flight across the barrier
            if (w < 2) asm volatile("s_waitcnt vmcnt(6)" ::: "memory");
            else       asm volatile("s_waitcnt vmcnt(7)" ::: "memory");
        } else {
            asm volatile("s_waitcnt vmcnt(0)" ::: "memory");
        }
        __builtin_amdgcn_s_barrier();          // all waves' S_t landed (raw barrier, no drain)
        compute(kt & 1);
        __builtin_amdgcn_s_barrier();          // all waves done reading buf before re-stage
    }

    // C/D layout: col = lane&15, row = (lane>>4)*4 + reg   [m89-verified]
#pragma unroll
    for (int mi = 0; mi < 4; mi++) {
#pragma unroll
        for (int ni = 0; ni < 5; ni++) {
            int gr0 = row0 + wr * 64 + mi * 16 + ks * 4;
            int gc = col0 + wc * 80 + ni * 16 + l15;
#pragma unroll
            for (int rr = 0; rr < 4; rr++) {
                int gr = gr0 + rr;
                if (gr < M) C[(size_t)gr * D + gc] = f2bf(acc[mi][ni][rr]);
            }
        }
    }
}

// ---------- s,t per (node, head) from bf16 Ht ----------
__global__ __launch_bounds__(256) void k_st(const ushort* __restrict__ Ht, const float* __restrict__ att_l,
                                            float* __restrict__ s_all, float* __restrict__ t_all, int n) {
    int gid = blockIdx.x * blockDim.x + threadIdx.x;
    if (gid >= n * HEADS) return;
    int i = gid >> 3, h = gid & 7;
    const uint2* hp2 = (const uint2*)(Ht + (size_t)i * D + h * HIDDEN);
    const float* As = att_l + h * 2 * HIDDEN;
    const float* At = As + HIDDEN;
    float s = 0.f, t = 0.f;
#pragma unroll 5
    for (int q = 0; q < 25; q++) {
        uint2 v = hp2[q];
        float f0 = bf2f((ushort)(v.x & 0xFFFF)), f1 = bf2f((ushort)(v.x >> 16));
        float f2 = bf2f((ushort)(v.y & 0xFFFF)), f3 = bf2f((ushort)(v.y >> 16));
        int c = q * 4;
        s += f0 * As[c] + f1 * As[c + 1] + f2 * As[c + 2] + f3 * As[c + 3];
        t += f0 * At[c] + f1 * At[c + 1] + f2 * At[c + 2] + f3 * At[c + 3];
    }
    s_all[gid] = s;
    t_all[gid] = t;
}

// ---------- per-node segment softmax + aggregate + relu + residual (x planes in-place) ----------
__global__ __launch_bounds__(256) void k_edge(const ushort* __restrict__ Ht, ushort* __restrict__ xh,
                                              ushort* __restrict__ xl,
                                              const float* __restrict__ s_all, const float* __restrict__ t_all,
                                              const int* __restrict__ dst, const int* __restrict__ row_ptr,
                                              int n) {
    int i = blockIdx.x;
    int t = threadIdx.x;
    __shared__ float lw[32][8];
    __shared__ int ld[32];
    int e0 = row_ptr[i], e1 = row_ptr[i + 1];
    int h = t / 25;            // head for aggregation (valid for t<200)
    int el = t >> 3, hh = t & 7;
    float s_ih = s_all[i * 8 + hh];
    float acc0 = 0, acc1 = 0, acc2 = 0, acc3 = 0, den = 0;

    for (int base = e0; base < e1; base += 32) {
        int cnt = min(32, e1 - base);
        __syncthreads();
        if (el < cnt) {
            int dd = dst[base + el];
            float ev = s_ih + t_all[dd * 8 + hh];
            ev = ev >= 0.f ? ev : ALPHA * ev;
            ev = fminf(fmaxf(ev, -2.f), 2.f);
            lw[el][hh] = __expf(ev);
            if (hh == 0) ld[el] = dd;
        }
        __syncthreads();
        if (t < 200) {
#pragma unroll 4
            for (int e = 0; e < cnt; e++) {
                int dd = ld[e];
                uint2 v = *(const uint2*)(Ht + (size_t)dd * D + t * 4);
                float wgt = lw[e][h];
                acc0 += wgt * bf2f((ushort)(v.x & 0xFFFF));
                acc1 += wgt * bf2f((ushort)(v.x >> 16));
                acc2 += wgt * bf2f((ushort)(v.y & 0xFFFF));
                acc3 += wgt * bf2f((ushort)(v.y >> 16));
                den += wgt;
            }
        }
    }
    if (t < 200) {
        size_t off = (size_t)i * D + t * 4;
        uint2 vh = *(uint2*)(xh + off);
        uint2 vl = *(uint2*)(xl + off);
        float x0 = bf2f((ushort)(vh.x & 0xFFFF)) + bf2f((ushort)(vl.x & 0xFFFF));
        float x1 = bf2f((ushort)(vh.x >> 16))    + bf2f((ushort)(vl.x >> 16));
        float x2 = bf2f((ushort)(vh.y & 0xFFFF)) + bf2f((ushort)(vl.y & 0xFFFF));
        float x3 = bf2f((ushort)(vh.y >> 16))    + bf2f((ushort)(vl.y >> 16));
        float inv = den > 0.f ? 1.f / den : 0.f;
        x0 += fmaxf(acc0 * inv, 0.f);
        x1 += fmaxf(acc1 * inv, 0.f);
        x2 += fmaxf(acc2 * inv, 0.f);
        x3 += fmaxf(acc3 * inv, 0.f);
        ushort h0 = f2bf(x0), h1 = f2bf(x1), h2 = f2bf(x2), h3 = f2bf(x3);
        ushort l0 = f2bf(x0 - bf2f(h0)), l1 = f2bf(x1 - bf2f(h1));
        ushort l2 = f2bf(x2 - bf2f(h2)), l3 = f2bf(x3 - bf2f(h3));
        *(uint2*)(xh + off) = make_uint2((uint)h0 | ((uint)h1 << 16), (uint)h2 | ((uint)h3 << 16));
        *(uint2*)(xl + off) = make_uint2((uint)l0 | ((uint)l1 << 16), (uint)l2 | ((uint)l3 << 16));
    }
}

// ---------- final stage A: per-block partial of sum_i (x_i . Wl + bl) * Wc_i ----------
__global__ __launch_bounds__(256) void k_final(const ushort* __restrict__ xh, const ushort* __restrict__ xl,
                                               const float* __restrict__ Wl, const float* __restrict__ bl,
                                               const float* __restrict__ Wc, float* __restrict__ fpart, int n) {
    __shared__ float part[4];
    int lane = threadIdx.x & 63, w = threadIdx.x >> 6;
    int wid = blockIdx.x * 4 + w;
    int nw = gridDim.x * 4;
    float p = 0.f;
    for (int i = wid; i < n; i += nw) {
        float dot = 0.f;
#pragma unroll
        for (int r = 0; r < 13; r++) {
            int j = r * 64 + lane;
            if (j < D) {
                size_t off = (size_t)i * D + j;
                dot += (bf2f(xh[off]) + bf2f(xl[off])) * Wl[j];
            }
        }
#pragma unroll
        for (int off = 32; off; off >>= 1) dot += __shfl_xor(dot, off);
        if (lane == 0) p += (dot + bl[0]) * Wc[i];
    }
    if (lane == 0) part[w] = p;
    __syncthreads();
    if (threadIdx.x == 0) fpart[blockIdx.x] = part[0] + part[1] + part[2] + part[3];
}

// ---------- final stage B ----------
__global__ __launch_bounds__(64) void k_reduce(const float* __restrict__ fpart, const float* __restrict__ bc,
                                               float* __restrict__ out, int nb) {
    if (threadIdx.x == 0) {
        float s = 0.f;
        for (int q = 0; q < nb; q++) s += fpart[q];
        out[0] = s + bc[0];
    }
}

// ---------- sentinel if workspace too small ----------
__global__ void k_sentinel(float* out) { out[0] = 12345.0f; }

extern "C" void kernel_launch(void* const* d_in, const int* in_sizes, int n_in,
                              void* d_out, int out_size, void* d_ws, size_t ws_size,
                              hipStream_t stream) {
    const float* ns   = (const float*)d_in[0];
    const int*   src  = (const int*)d_in[1];
    const int*   dst  = (const int*)d_in[2];
    const float* Wpre = (const float*)d_in[3];
    const float* bpre = (const float*)d_in[4];
    const float* kern = (const float*)d_in[5];
    const float* att  = (const float*)d_in[6];
    const float* Wl   = (const float*)d_in[7];
    const float* bl   = (const float*)d_in[8];
    const float* Wc   = (const float*)d_in[9];
    const float* bc   = (const float*)d_in[10];
    int n = in_sizes[9];   // Wc has n elements
    int E = in_sizes[1];

    size_t need = 0;
    auto sz = [&](size_t bytes) { size_t o = need; need += (bytes + 255) & ~255ull; return o; };
    size_t o_xh    = sz((size_t)n * D * 2);          // bf16 hi plane of x
    size_t o_xl    = sz((size_t)n * D * 2);          // bf16 lo plane of x
    size_t o_Ht    = sz((size_t)n * D * 2);          // bf16 Ht
    size_t o_bsp   = sz(3ull * D * D * 2);           // bf16 transposed weights (hi only)
    size_t o_s     = sz((size_t)n * 8 * 4);
    size_t o_t     = sz((size_t)n * 8 * 4);
    size_t o_rp    = sz(((size_t)n + 1) * 4);
    size_t o_fp    = sz(128 * 4);

    if (need > ws_size) {   // diagnostic: absmax will be ~12345
        k_sentinel<<<1, 1, 0, stream>>>((float*)d_out);
        return;
    }

    char* ws = (char*)d_ws;
    ushort* xh    = (ushort*)(ws + o_xh);
    ushort* xl    = (ushort*)(ws + o_xl);
    ushort* Ht    = (ushort*)(ws + o_Ht);
    ushort* bsp   = (ushort*)(ws + o_bsp);
    float*  s_all = (float*)(ws + o_s);
    float*  t_all = (float*)(ws + o_t);
    int*    row_ptr = (int*)(ws + o_rp);
    float*  fpart = (float*)(ws + o_fp);

    k_rowptr<<<(n + 1 + 255) / 256, 256, 0, stream>>>(src, E, n, row_ptr);
    k_repack<<<(3 * D * D + 255) / 256, 256, 0, stream>>>(kern, bsp);
    dim3 gpre((D + 255) / 256, (n + 31) / 32);
    k_pre<<<gpre, 256, 0, stream>>>(ns, Wpre, bpre, xh, xl, n);

    int nrb = (n + 127) / 128;                    // 391 row blocks
    int grid_g = 8 * (((nrb + 7) / 8) * 5);       // swizzle-decoded inside kernel
    for (int l = 0; l < 3; l++) {
        k_gemm<<<grid_g, 256, 0, stream>>>(xh, xl, bsp + (size_t)l * D * D, Ht, n);
        k_st<<<(n * HEADS + 255) / 256, 256, 0, stream>>>(Ht, att + l * HEADS * 2 * HIDDEN, s_all, t_all, n);
        k_edge<<<n, 256, 0, stream>>>(Ht, xh, xl, s_all, t_all, dst, row_ptr, n);
    }

    k_final<<<120, 256, 0, stream>>>(xh, xl, Wl, bl, Wc, fpart, n);
    k_reduce<<<1, 64, 0, stream>>>(fpart, bc, (float*)d_out, 120);
}